// Round 1
// 152.019 us; speedup vs baseline: 1.0598x; 1.0598x over previous
//
#include <hip/hip_runtime.h>
#include <math.h>

// Problem constants (fixed by the reference).
#define NUM_K   512        // codebook entries
#define DIM     64         // embedding dim (== C)
#define NROWS   131072     // 32*64*64 flattened (b,h,w) rows
#define NELEM   8388608    // NROWS*DIM
// d_out layout (float32, concatenated in return order):
// [0] loss ; [1..1+NELEM) quantized NCHW ; [1+NELEM] perplexity ;
// [2+NELEM..) codebook_indices (as float)
#define Q_OFF    1
#define PERP_OFF 8388609
#define IDX_OFF  8388610

// Candidate margin. Approx-score error sources:
//  (a) bf16 hi/lo MFMA (incl. dropped xl*wl): eps <= 1.2e-5
//  (b) packing k into the low 9 mantissa bits of s (this round):
//      |delta| <= |s| * 2^-14 <= 1.6e-5  (|s| <= 2*||x||*||w|| + wsq <= 0.26)
//  (c) reference fp32 grid noise eta <= 1.52e-5
// Need M > 2*(eps+delta) + 2*eta = 8.6e-5. M = 1.7e-4 keeps ~2x safety.
// ks with packed s' > g1+M provably cannot be the reference argmin;
// candidates get frozen bitwise evaluation; >=3 same-lane-class candidates
// within M trigger the full exact rescan (unchanged safety net).
#define MARGIN  1.7e-4f

typedef short  bf16x8 __attribute__((ext_vector_type(8)));
typedef float  f32x4  __attribute__((ext_vector_type(4)));

// ws layout (host-computed; REP = power-of-2 replica count for counts):
//   [0,4)                          float loss_sum
//   [8,12)                         uint  ticket
//   [64, 64+REP*2048)              uint  counts[REP][512]
//   [64+REP*2048, +2048)           float swsq_g[512]   (frozen ||w_k||^2)
//   [64+REP*2048+2048, +131072)    ushort wpack[65536] (B-frag hi/lo codebook)
// REP=2 footprint = 137280 B <= the previous kernel's 139264 B use, so any
// workspace that ran the old kernel fits REP>=2; REP=16 needs 165952 B.

__device__ __forceinline__ unsigned short f2bf(float f) {  // RNE f32->bf16
    unsigned u = __float_as_uint(f);
    return (unsigned short)((u + 0x7FFFu + ((u >> 16) & 1u)) >> 16);
}
__device__ __forceinline__ float bf2f(unsigned short h) {
    return __uint_as_float(((unsigned)h) << 16);
}

// Frozen bitwise reference score (verified): sequential fmaf chain c=0..63,
// s = fl(fl(xsq+wsq)-fl(2*dot)). Packed (bits(s)<<32)|k: s>0 always (~64),
// so u64 min = lexicographic (s,k) = np.argmin first-occurrence rule.
__device__ __forceinline__ unsigned long long eval_chain(
        const float* __restrict__ xr, float xsq,
        const float* __restrict__ w, float wsq, int k) {
    const float* wk = w + (size_t)k * DIM;
    float d = 0.f;
#pragma unroll
    for (int c = 0; c < DIM; c += 4) {
        float4 wv = *(const float4*)(wk + c);
        d = fmaf(xr[c + 0], wv.x, d);
        d = fmaf(xr[c + 1], wv.y, d);
        d = fmaf(xr[c + 2], wv.z, d);
        d = fmaf(xr[c + 3], wv.w, d);
    }
    float s = __fsub_rn(__fadd_rn(xsq, wsq), __fmul_rn(2.f, d));
    return ((unsigned long long)__float_as_uint(s) << 32) | (unsigned)k;
}

// Prep: frozen wsq + B-fragment hi/lo packing for mfma_f32_16x16x32_bf16
// (B[k=(lane>>4)*8+j][n=lane&15]). Also zeroes loss/ticket/counts (replaces
// the hipMemsetAsync dispatch; 8192 threads cover up to 16*512 counters).
__global__ __launch_bounds__(256) void vq_prep(const float* __restrict__ w,
                                               float* __restrict__ swsq_g,
                                               unsigned short* __restrict__ wpack,
                                               unsigned* __restrict__ counts,
                                               int rep_words,
                                               float* __restrict__ loss_sum,
                                               unsigned* __restrict__ ticket) {
    const int id = blockIdx.x * 256 + threadIdx.x;   // 0..8191
    if (id < rep_words) counts[id] = 0u;
    if (id == 0) { loss_sum[0] = 0.f; ticket[0] = 0u; }
    if (id < NUM_K) {
        const float* wk = w + id * DIM;
        float r[8];
#pragma unroll
        for (int j = 0; j < 8; ++j) r[j] = __fmul_rn(wk[j], wk[j]);
#pragma unroll
        for (int t = 1; t < 8; ++t)
#pragma unroll
            for (int j = 0; j < 8; ++j)
                r[j] = __fadd_rn(r[j], __fmul_rn(wk[8 * t + j], wk[8 * t + j]));
        swsq_g[id] = __fadd_rn(
            __fadd_rn(__fadd_rn(r[0], r[1]), __fadd_rn(r[2], r[3])),
            __fadd_rn(__fadd_rn(r[4], r[5]), __fadd_rn(r[6], r[7])));
    }
    const int kt = id >> 8, f = (id >> 6) & 3, l = id & 63;
    const int step = f >> 1, pass = f & 1;
    const int coln = kt * 16 + (l & 15), quad = l >> 4;
    const float* src = w + (size_t)coln * DIM + step * 32 + quad * 8;
    unsigned short tmp[8];
#pragma unroll
    for (int j = 0; j < 8; ++j) {
        float v = src[j];
        unsigned short hi = f2bf(v);
        tmp[j] = pass ? f2bf(v - bf2f(hi)) : hi;
    }
    *(uint4*)(wpack + (size_t)id * 8) = *(uint4*)tmp;
}

// Main kernel: MFMA approx pass with k packed into the low 9 mantissa bits
// of the score (pure med3/min value-sort, no index cndmasks) -> in-block
// frozen exact evaluation of candidates -> rare full rescans -> epilogue.
// The last block (atomic ticket) also produces loss/perplexity, reproducing
// the old vq_final reduction tree bitwise.
__global__ __launch_bounds__(256, 3) void vq_phase1(
        const float* __restrict__ x,
        const float* __restrict__ w,
        const float* __restrict__ swsq_g,
        const uint4* __restrict__ wpack,
        float* __restrict__ out,
        float* __restrict__ loss_sum,
        unsigned* __restrict__ counts,
        unsigned* __restrict__ ticket,
        int rep_mask) {
    __shared__ float swsq[NUM_K];              // 2 KB
    __shared__ unsigned hcnt[NUM_K];           // 2 KB
    __shared__ float xs[128 * 65];             // x rows, stride 65: 33.3 KB
    __shared__ float sxsq[128];                // frozen xsq per row
    __shared__ int sidx[128];                  // final index per row
    __shared__ float wred[4];
    __shared__ unsigned long long rred[4];
    __shared__ int rlist[128];
    __shared__ int rcount;
    __shared__ unsigned s_tick;
    __shared__ float red8[8];

    const int tid  = threadIdx.x;
    const int lane = tid & 63;
    const int wvid = tid >> 6;
    const int quad = lane >> 4;
    const int m    = lane & 15;
    const int n0   = blockIdx.x * 128;
    const int b    = n0 >> 12;
    const int hw0  = n0 & 4095;
    const float* xbase = x + (size_t)b * 262144 + hw0;
    float* out_q   = out + Q_OFF;
    float* out_idx = out + IDX_OFF;

    if (tid == 0) rcount = 0;
    for (int i = tid; i < NUM_K; i += 256) { swsq[i] = swsq_g[i]; hcnt[i] = 0; }

    // Stage x -> xs (stride-65: conflict-free) + A fragments in registers.
    bf16x8 afr[2][2][2];
#pragma unroll
    for (int rt = 0; rt < 2; ++rt) {
        const int row = wvid * 32 + rt * 16 + m;
        const float* xp = xbase + row;
#pragma unroll
        for (int s = 0; s < 2; ++s) {
            union { bf16x8 v; unsigned short u[8]; } hi, lo;
#pragma unroll
            for (int j = 0; j < 8; ++j) {
                const int c = s * 32 + quad * 8 + j;
                float v = xp[(size_t)c * 4096];
                xs[row * 65 + c] = v;
                unsigned short h = f2bf(v);
                hi.u[j] = h;
                lo.u[j] = f2bf(v - bf2f(h));
            }
            afr[rt][s][0] = hi.v;
            afr[rt][s][1] = lo.v;
        }
    }
    __syncthreads();   // xs ready

    // Frozen xsq per row (bitwise same form as verified rounds).
    if (tid < 128) {
        const float* xr = &xs[tid * 65];
        float p0 = 0.f, p1 = 0.f, p2 = 0.f, p3 = 0.f;
#pragma unroll
        for (int c = 0; c < DIM; c += 4) {
            p0 = fmaf(xr[c + 0], xr[c + 0], p0);
            p1 = fmaf(xr[c + 1], xr[c + 1], p1);
            p2 = fmaf(xr[c + 2], xr[c + 2], p2);
            p3 = fmaf(xr[c + 3], xr[c + 3], p3);
        }
        sxsq[tid] = __fadd_rn(__fadd_rn(p0, p1), __fadd_rn(p2, p3));
    }
    __syncthreads();   // sxsq/swsq/rcount ready

    // Approx k-loop. Scores carry their k in the low 9 mantissa bits, so
    // top-3 tracking is a pure value sorting network (med3,med3,min).
    float m1v[2][4], m2v[2][4], m3v[2][4];
#pragma unroll
    for (int rt = 0; rt < 2; ++rt)
#pragma unroll
        for (int r = 0; r < 4; ++r) {
            m1v[rt][r] = 3.4e38f; m2v[rt][r] = 3.4e38f; m3v[rt][r] = 3.4e38f;
        }

    uint4 P[2][4];
    {
        const uint4* t0 = wpack;
        const uint4* t1 = wpack + 256;
#pragma unroll
        for (int q = 0; q < 4; ++q) { P[0][q] = t0[q * 64 + lane];
                                      P[1][q] = t1[q * 64 + lane]; }
    }
#pragma unroll 1
    for (int kt = 0; kt < 32; kt += 2) {
#pragma unroll
        for (int h = 0; h < 2; ++h) {
            bf16x8 bh0 = __builtin_bit_cast(bf16x8, P[h][0]);
            bf16x8 bl0 = __builtin_bit_cast(bf16x8, P[h][1]);
            bf16x8 bh1 = __builtin_bit_cast(bf16x8, P[h][2]);
            bf16x8 bl1 = __builtin_bit_cast(bf16x8, P[h][3]);
            const int kg = (kt + h) * 16 + m;
            const float wsqv = swsq[kg];
            if (kt + h + 2 < 32) {
                const uint4* np = wpack + (size_t)(kt + h + 2) * 256;
#pragma unroll
                for (int q = 0; q < 4; ++q) P[h][q] = np[q * 64 + lane];
            }
#pragma unroll
            for (int rt = 0; rt < 2; ++rt) {
                f32x4 acc = {0.f, 0.f, 0.f, 0.f};
                acc = __builtin_amdgcn_mfma_f32_16x16x32_bf16(afr[rt][0][0], bh0, acc, 0, 0, 0);
                acc = __builtin_amdgcn_mfma_f32_16x16x32_bf16(afr[rt][0][0], bl0, acc, 0, 0, 0);
                acc = __builtin_amdgcn_mfma_f32_16x16x32_bf16(afr[rt][0][1], bh0, acc, 0, 0, 0);
                acc = __builtin_amdgcn_mfma_f32_16x16x32_bf16(afr[rt][1][0], bh1, acc, 0, 0, 0);
                acc = __builtin_amdgcn_mfma_f32_16x16x32_bf16(afr[rt][1][0], bl1, acc, 0, 0, 0);
                acc = __builtin_amdgcn_mfma_f32_16x16x32_bf16(afr[rt][1][1], bh1, acc, 0, 0, 0);
#pragma unroll
                for (int r = 0; r < 4; ++r) {
                    float s  = fmaf(-2.f, acc[r], wsqv);
                    float sp = __uint_as_float(
                        (__float_as_uint(s) & 0xFFFFFE00u) | (unsigned)kg);
                    m3v[rt][r] = __builtin_amdgcn_fmed3f(m2v[rt][r], m3v[rt][r], sp);
                    m2v[rt][r] = __builtin_amdgcn_fmed3f(m1v[rt][r], m2v[rt][r], sp);
                    m1v[rt][r] = fminf(m1v[rt][r], sp);
                }
            }
        }
    }

    // 8 independent 16-lane min trees, unrolled for ILP (no index swaps:
    // the packed value carries its k).
    float gm[2][4];
#pragma unroll
    for (int rt = 0; rt < 2; ++rt)
#pragma unroll
        for (int r = 0; r < 4; ++r) {
            float g = m1v[rt][r];
            g = fminf(g, __shfl_xor(g, 1));
            g = fminf(g, __shfl_xor(g, 2));
            g = fminf(g, __shfl_xor(g, 4));
            g = fminf(g, __shfl_xor(g, 8));
            gm[rt][r] = g;
        }

    // Per-rowslot resolution: candidate exact chains, u64 reduce.
#pragma unroll 1
    for (int rt = 0; rt < 2; ++rt)
#pragma unroll 1
        for (int r = 0; r < 4; ++r) {
            const float lim = gm[rt][r] + MARGIN;
            const bool c1 = m1v[rt][r] <= lim;
            const bool c2 = m2v[rt][r] <= lim;
            const bool f3 = m3v[rt][r] <= lim;
            unsigned long long b1 = __ballot(c1);
            unsigned long long b2 = __ballot(c2);
            unsigned long long b3 = __ballot(f3);
            const unsigned fld1 = (unsigned)(b1 >> (quad * 16)) & 0xFFFFu;
            const unsigned fld2 = (unsigned)(b2 >> (quad * 16)) & 0xFFFFu;
            const unsigned fld3 = (unsigned)(b3 >> (quad * 16)) & 0xFFFFu;
            const int  nc   = __popc(fld1) + __popc(fld2);
            const bool flag = fld3 != 0;   // >=3 same-class within M: rescan
            const int rowL = wvid * 32 + rt * 16 + quad * 4 + r;
            unsigned long long best = ~0ull;
            if (!flag && nc > 1) {
                const float* xr = &xs[rowL * 65];
                const float xq = sxsq[rowL];
                if (c1) {
                    const int ka = (int)(__float_as_uint(m1v[rt][r]) & 511u);
                    best = eval_chain(xr, xq, w, swsq[ka], ka);
                }
                if (c2) {
                    const int kb = (int)(__float_as_uint(m2v[rt][r]) & 511u);
                    unsigned long long e = eval_chain(xr, xq, w, swsq[kb], kb);
                    best = e < best ? e : best;
                }
            }
#pragma unroll
            for (int d = 1; d < 16; d <<= 1) {
                unsigned long long o = __shfl_xor(best, d);
                best = o < best ? o : best;
            }
            if (m == 0) {
                if (flag) rlist[atomicAdd(&rcount, 1)] = rowL;
                else sidx[rowL] = (nc > 1)
                        ? (int)(best & 0xFFFFFFFFull)
                        : (int)(__float_as_uint(gm[rt][r]) & 511u);
            }
        }
    __syncthreads();   // sidx (candidate path) + rlist/rcount ready

    // Full exact rescan for flagged rows (rare): whole block, 2 k/thread.
    const int rc = rcount;
#pragma unroll 1
    for (int i = 0; i < rc; ++i) {
        const int rowL = rlist[i];
        const float* xr = &xs[rowL * 65];
        const float xq = sxsq[rowL];
        unsigned long long bb = eval_chain(xr, xq, w, swsq[tid], tid);
        unsigned long long e2 = eval_chain(xr, xq, w, swsq[tid + 256], tid + 256);
        if (e2 < bb) bb = e2;
#pragma unroll
        for (int d = 1; d < 64; d <<= 1) {
            unsigned long long o = __shfl_xor(bb, d);
            if (o < bb) bb = o;
        }
        if (lane == 0) rred[wvid] = bb;
        __syncthreads();
        if (tid == 0) {
            unsigned long long q0 = rred[0] < rred[1] ? rred[0] : rred[1];
            unsigned long long q1 = rred[2] < rred[3] ? rred[2] : rred[3];
            sidx[rowL] = (int)((q0 < q1 ? q0 : q1) & 0xFFFFFFFFull);
        }
        __syncthreads();
    }

    // Epilogue: thread (rb=tid&127, cg=tid>>7) handles 32 channels of row rb;
    // x from LDS (no global re-read).
    {
        const int rb = tid & 127, cg = tid >> 7;
        const int bk = sidx[rb];
        const float* xr = &xs[rb * 65];
        float dsum = 0.f;
        const float4* wb = (const float4*)(w + (size_t)bk * DIM + cg * 32);
        float* oq = out_q + (size_t)b * 262144 + hw0 + rb;
        if (cg == 0) {
            out_idx[n0 + rb] = (float)bk;
            atomicAdd(&hcnt[bk], 1u);
        }
#pragma unroll
        for (int j4 = 0; j4 < 8; ++j4) {
            float4 v = wb[j4];
            const int c = cg * 32 + j4 * 4;
            float e0 = v.x - xr[c + 0];
            float e1 = v.y - xr[c + 1];
            float e2 = v.z - xr[c + 2];
            float e3 = v.w - xr[c + 3];
            dsum = fmaf(e0, e0, dsum);
            dsum = fmaf(e1, e1, dsum);
            dsum = fmaf(e2, e2, dsum);
            dsum = fmaf(e3, e3, dsum);
            oq[(size_t)(c + 0) * 4096] = v.x;
            oq[(size_t)(c + 1) * 4096] = v.y;
            oq[(size_t)(c + 2) * 4096] = v.z;
            oq[(size_t)(c + 3) * 4096] = v.w;
        }
#pragma unroll
        for (int off = 32; off > 0; off >>= 1) dsum += __shfl_down(dsum, off);
        if (lane == 0) wred[wvid] = dsum;
    }
    __syncthreads();
    if (tid == 0)
        atomicAdd(loss_sum, (wred[0] + wred[1]) + (wred[2] + wred[3]));
    {
        unsigned* mycnt = counts + ((blockIdx.x & rep_mask) << 9);
        for (int i = tid; i < NUM_K; i += 256) {
            unsigned cc = hcnt[i];
            if (cc) atomicAdd(&mycnt[i], cc);
        }
    }

    // Ticket: the barrier's vmcnt(0) drain guarantees this block's counts/
    // loss atomics are acked at the coherent point before the ticket RMW.
    __syncthreads();
    if (tid == 0) s_tick = atomicAdd(ticket, 1u);
    __syncthreads();
    if (s_tick == (unsigned)(gridDim.x - 1)) {
        // Folded vq_final: bitwise-identical reduction tree (8 virtual
        // 64-lane waves, same shfl_down butterfly, same partial order).
        // counts/loss read via atomics -> coherent regardless of XCD L2s.
#pragma unroll 1
        for (int half = 0; half < 2; ++half) {
            const int k = (wvid + half * 4) * 64 + lane;
            unsigned cnt = 0;
            for (int rr = 0; rr <= rep_mask; ++rr)
                cnt += atomicAdd(&counts[(rr << 9) + k], 0u);
            float p = (float)cnt * (1.f / (float)NROWS);  // /131072 exact
            float t = p * logf(p + 1e-10f);
#pragma unroll
            for (int off = 32; off > 0; off >>= 1) t += __shfl_down(t, off);
            if (lane == 0) red8[wvid + half * 4] = t;
        }
        __syncthreads();
        if (tid == 0) {
            float s = 0.f;
#pragma unroll
            for (int i = 0; i < 8; ++i) s += red8[i];
            out[PERP_OFF] = expf(-s);
            // loss = q_latent + 0.25*e_latent = 1.25 * MSE (forward equal)
            float ls = atomicAdd(loss_sum, 0.f);
            out[0] = ls * (1.25f / (float)NELEM);
        }
    }
}

extern "C" void kernel_launch(void* const* d_in, const int* in_sizes, int n_in,
                              void* d_out, int out_size, void* d_ws, size_t ws_size,
                              hipStream_t stream) {
    const float* x = (const float*)d_in[0];
    const float* w = (const float*)d_in[1];
    float* out = (float*)d_out;
    char* ws = (char*)d_ws;

    // Histogram replica count: as many as fit (power of 2, <=16). rep=2
    // footprint (137280 B) <= the previous kernel's workspace use, so this
    // always fits a workspace the old kernel ran in.
    int rep = 16;
    while (rep > 2 && (size_t)(64 + rep * 2048 + 2048 + 131072) > ws_size)
        rep >>= 1;

    float*    loss_sum = (float*)ws;
    unsigned* ticket   = (unsigned*)(ws + 8);
    unsigned* counts   = (unsigned*)(ws + 64);
    float*    swsq_g   = (float*)(ws + 64 + rep * 2048);
    unsigned short* wpack = (unsigned short*)(ws + 64 + rep * 2048 + 2048);

    // No memset dispatch: vq_prep zeroes loss/ticket/counts.
    vq_prep<<<32, 256, 0, stream>>>(w, swsq_g, wpack, counts, rep * 512,
                                    loss_sum, ticket);
    vq_phase1<<<NROWS / 128, 256, 0, stream>>>(x, w, swsq_g, (const uint4*)wpack,
                                               out, loss_sum, counts, ticket,
                                               rep - 1);
}